// Round 10
// baseline (85.131 us; speedup 1.0000x reference)
//
#include <hip/hip_runtime.h>

// Problem constants (from reference)
#define NF 10000
#define LL 100000

typedef float f32x2 __attribute__((ext_vector_type(2)));
typedef float f32x4 __attribute__((ext_vector_type(4)));

constexpr int BC    = 64;                    // B*C
constexpr int TL    = 64;                    // l's per main block
constexpr int NBLK  = (LL + TL - 1) / TL;    // 1563
constexpr int BLOCK = 256;                   // 4 waves
constexpr int NW    = BLOCK / 64;            // 4
constexpr int CSTR  = 65;                    // corr [slot][bc] stride in uint (pad)

constexpr int TNF  = 16;                     // nf rows per prep block
constexpr int TBLK = NF / TNF;               // 625

// workspace layout
constexpr size_t WS_ACC  = 0;     // double
constexpr size_t WS_DONE = 8;     // int
constexpr size_t WS_TBL  = 256;   // f32x4[NF*BC] = 10,240,000 B
constexpr size_t WS_NEED = WS_TBL + (size_t)NF * BC * 16;

// bf16 pack/unpack (RNE)
__device__ __forceinline__ unsigned pack_bf16(float a, float b) {
    unsigned ua = __float_as_uint(a), ub = __float_as_uint(b);
    ua = (ua + 0x7FFFu + ((ua >> 16) & 1u)) >> 16;
    ub = (ub + 0x7FFFu + ((ub >> 16) & 1u)) >> 16;
    return ua | (ub << 16);
}
__device__ __forceinline__ float lo_bf16(unsigned w) { return __uint_as_float(w << 16); }
__device__ __forceinline__ float hi_bf16(unsigned w) { return __uint_as_float(w & 0xFFFF0000u); }

// ---------- prep: transpose (fgap, t_f) -> tbl[nf][bc] float4; init counters ----------
__global__ __launch_bounds__(256) void k_prep(
    const float2* __restrict__ i_f, const float2* __restrict__ t_f,
    f32x4* __restrict__ tbl, double* __restrict__ acc, int* __restrict__ done)
{
    if (blockIdx.x == 0 && threadIdx.x == 0) { *acc = 0.0; *done = 0; }
    __shared__ f32x4 t4[BC][TNF + 1];
    const int nf0 = blockIdx.x * TNF;
    const int tid = threadIdx.x;
    const int c = tid & 15;          // nf within tile
    const int r = tid >> 4;          // bc start
    for (int bc = r; bc < BC; bc += 16) {
        float2 iv = i_f[(size_t)bc * NF + nf0 + c];
        float2 tv = t_f[(size_t)bc * NF + nf0 + c];
        t4[bc][c] = (f32x4){iv.x - tv.x, iv.y - tv.y, tv.x, tv.y};
    }
    __syncthreads();
    const int lane = tid & 63;
    const int w    = tid >> 6;
    for (int j = w; j < TNF; j += 4)
        tbl[(size_t)(nf0 + j) * BC + lane] = t4[lane][j];
}

// ---------- main: R3 structure + bf16 corr LDS + ballot classify + fused finalize ----------
__global__ __launch_bounds__(BLOCK) void k_main8(
    const float* __restrict__ i_s, const float* __restrict__ t_s,
    const int2*  __restrict__ xi,  const f32x2* __restrict__ ks,
    const f32x4* __restrict__ tbl,
    double* __restrict__ acc, int* __restrict__ done, float* __restrict__ out)
{
    __shared__ unsigned corrw[TL * CSTR];   // [slot][bc] bf16-packed = 16,640 B
    __shared__ int2  xi_list[TL];
    __shared__ int   pos[TL];
    __shared__ int   cnt_s;
    __shared__ float wsum[NW];

    const int l0   = blockIdx.x * TL;
    const int tlb  = min(TL, LL - l0);
    const int tid  = threadIdx.x;
    const int lane = tid & 63;
    const int wid  = tid >> 6;

    // wave-0 ballot classify + compaction
    if (wid == 0) {
        const bool live = lane < tlb;
        f32x2 kv = {1.f, 1.f};
        int2  iv = {0, 0};
        if (live) { kv = ks[l0 + lane]; iv = xi[l0 + lane]; }
        const bool act = live && !(kv.x > 0.f) && !(kv.y > 0.f);
        const unsigned long long m = __ballot(act);
        const int slot = __popcll(m & ((1ull << lane) - 1ull));
        pos[lane] = act ? slot : -1;
        if (act) xi_list[slot] = iv;
        if (lane == 0) cnt_s = (int)__popcll(m);
    }
    __syncthreads();

    // gather: one wave per active slot reads 2 coalesced 1KB table rows
    const int nact = cnt_s;
    for (int a = wid; a < nact; a += NW) {
        int2 idx = xi_list[a];
        f32x4 r0 = tbl[(size_t)idx.x * BC + lane];   // (f0, tf0)
        f32x4 r1 = tbl[(size_t)idx.y * BC + lane];   // (f1, tf1)
        // corr = cmul_conj(f0,tf1) + cmul_conj(tf0,f1)
        float cr = r0.x * r1.z + r0.y * r1.w + r0.z * r1.x + r0.w * r1.y;
        float ci = r0.y * r1.z - r0.x * r1.w + r0.w * r1.x - r0.z * r1.y;
        corrw[a * CSTR + lane] = pack_bf16(cr, ci);
    }
    __syncthreads();

    // streams: lane <-> l (coalesced 512B), loop over bc per wave  (R3-identical shape)
    float sum = 0.f;
    if (lane < tlb) {
        const int l = l0 + lane;
        const int myslot = pos[lane];
        for (int bc = wid; bc < BC; bc += NW) {
            f32x2 si = __builtin_nontemporal_load((const f32x2*)(i_s + 2 * ((size_t)bc * LL + l)));
            f32x2 st = __builtin_nontemporal_load((const f32x2*)(t_s + 2 * ((size_t)bc * LL + l)));
            float gr = si.x - st.x;
            float gi = si.y - st.y;
            if (myslot >= 0) {
                unsigned cw = corrw[myslot * CSTR + bc];
                gr -= lo_bf16(cw);
                gi -= hi_bf16(cw);
            }
            sum += gr * gr + gi * gi;
        }
    }

    #pragma unroll
    for (int off = 32; off; off >>= 1) sum += __shfl_down(sum, off, 64);
    if (lane == 0) wsum[wid] = sum;
    __syncthreads();
    if (tid == 0) {
        float t = wsum[0] + wsum[1] + wsum[2] + wsum[3];
        atomicAdd(acc, (double)t);
        __threadfence();
        int prev = atomicAdd(done, 1);
        if (prev == NBLK - 1) {
            __threadfence();
            double total = atomicAdd(acc, 0.0);
            out[0] = (float)(total / (double)((size_t)BC * LL));
        }
    }
}

// ---------- fallback (round-1 kernel) if workspace too small ----------
constexpr int FCHUNKS = 32;
constexpr int FCHUNK  = (LL + FCHUNKS - 1) / FCHUNKS;

__global__ __launch_bounds__(256) void mse_fallback(
    const float* __restrict__ i_f, const float* __restrict__ i_s,
    const float* __restrict__ t_f, const float* __restrict__ t_s,
    const int*  __restrict__ xi,  const float* __restrict__ ks,
    double* __restrict__ acc)
{
    const int bc    = blockIdx.x / FCHUNKS;
    const int chunk = blockIdx.x % FCHUNKS;
    const int l0 = chunk * FCHUNK;
    const int l1 = (l0 + FCHUNK < LL) ? (l0 + FCHUNK) : LL;

    const float2* isv = (const float2*)i_s + (size_t)bc * LL;
    const float2* tsv = (const float2*)t_s + (size_t)bc * LL;
    const float2* ifv = (const float2*)i_f + (size_t)bc * NF;
    const float2* tfv = (const float2*)t_f + (size_t)bc * NF;
    const int2*   xiv = (const int2*)xi;
    const float2* ksv = (const float2*)ks;

    float sum = 0.f;
    for (int l = l0 + (int)threadIdx.x; l < l1; l += 256) {
        float2 si = isv[l], st = tsv[l];
        float gr = si.x - st.x, gi = si.y - st.y;
        float2 k = ksv[l];
        if (!(k.x > 0.f) && !(k.y > 0.f)) {
            int2 idx = xiv[l];
            float2 tf0 = tfv[idx.x], if0 = ifv[idx.x];
            float2 tf1 = tfv[idx.y], if1 = ifv[idx.y];
            float f0r = if0.x - tf0.x, f0i = if0.y - tf0.y;
            float f1r = if1.x - tf1.x, f1i = if1.y - tf1.y;
            gr -= f0r * tf1.x + f0i * tf1.y;
            gi -= f0i * tf1.x - f0r * tf1.y;
            gr -= tf0.x * f1r + tf0.y * f1i;
            gi -= tf0.y * f1r - tf0.x * f1i;
        }
        sum += gr * gr + gi * gi;
    }
    #pragma unroll
    for (int off = 32; off; off >>= 1) sum += __shfl_down(sum, off, 64);
    __shared__ float ws[4];
    const int lane = threadIdx.x & 63, wwid = threadIdx.x >> 6;
    if (lane == 0) ws[wwid] = sum;
    __syncthreads();
    if (threadIdx.x == 0) {
        float t = ws[0] + ws[1] + ws[2] + ws[3];
        atomicAdd(acc, (double)t);
    }
}

__global__ void mse_finalize(const double* __restrict__ acc, float* __restrict__ out)
{
    out[0] = (float)(acc[0] / (double)((size_t)BC * LL));
}

extern "C" void kernel_launch(void* const* d_in, const int* in_sizes, int n_in,
                              void* d_out, int out_size, void* d_ws, size_t ws_size,
                              hipStream_t stream)
{
    const float* i_f = (const float*)d_in[0];
    const float* i_s = (const float*)d_in[1];
    const float* t_f = (const float*)d_in[2];
    const float* t_s = (const float*)d_in[3];
    const int*   xi  = (const int*)d_in[4];
    const float* ks  = (const float*)d_in[5];
    float* out = (float*)d_out;

    char* ws = (char*)d_ws;
    double* acc  = (double*)(ws + WS_ACC);
    int*    done = (int*)(ws + WS_DONE);

    if (ws_size >= WS_NEED) {
        f32x4* tbl = (f32x4*)(ws + WS_TBL);
        k_prep<<<TBLK, 256, 0, stream>>>((const float2*)i_f, (const float2*)t_f,
                                         tbl, acc, done);
        k_main8<<<NBLK, BLOCK, 0, stream>>>(
            i_s, t_s, (const int2*)xi, (const f32x2*)ks, tbl, acc, done, out);
    } else {
        (void)hipMemsetAsync(ws, 0, 16, stream);
        mse_fallback<<<BC * FCHUNKS, 256, 0, stream>>>(
            i_f, i_s, t_f, t_s, xi, ks, acc);
        mse_finalize<<<1, 1, 0, stream>>>(acc, out);
    }
}